// Round 2
// baseline (550.255 us; speedup 1.0000x reference)
//
#include <hip/hip_runtime.h>

// Problem constants (from reference): BS=16384, DEMO_DIM=32, FEAT_DIM=256
// out[b,i,f] = x[b,i] * W[i,f] + b[i,f]   (all fp32)
// Memory-bound: 512 MiB write, ~2 MiB read. Target ~85 us at 6.3 TB/s.

#define BS_N      16384
#define DEMO_DIM  32
#define FEAT_DIM  256

// Clang native vector type: accepted by __builtin_nontemporal_store
// (HIP's float4 struct is not).
typedef float vf4 __attribute__((ext_vector_type(4)));

__global__ __launch_bounds__(256) void demoproj_kernel(
    const float* __restrict__ x,   // (BS, DEMO_DIM)
    const float* __restrict__ W,   // (DEMO_DIM, FEAT_DIM)
    const float* __restrict__ B,   // (DEMO_DIM, FEAT_DIM)
    float* __restrict__ out)       // (BS, DEMO_DIM, FEAT_DIM)
{
    // One vf4 of output per thread. f-row is 256 floats = 64 vf4s,
    // so a 64-lane wave covers exactly one (b,i) row: x/W/B accesses are
    // wave-uniform-row -> broadcast from L1/L2.
    const size_t g = (size_t)blockIdx.x * blockDim.x + threadIdx.x;
    const size_t e = g << 2;                 // element index of first float
    const int    f = (int)(e & (FEAT_DIM - 1));
    const size_t row = e >> 8;               // = b*DEMO_DIM + i
    const int    i = (int)(row & (DEMO_DIM - 1));

    const float xv = x[row];

    const vf4 wv = *reinterpret_cast<const vf4*>(W + (size_t)i * FEAT_DIM + f);
    const vf4 bv = *reinterpret_cast<const vf4*>(B + (size_t)i * FEAT_DIM + f);

    vf4 o;
    o.x = fmaf(xv, wv.x, bv.x);
    o.y = fmaf(xv, wv.y, bv.y);
    o.z = fmaf(xv, wv.z, bv.z);
    o.w = fmaf(xv, wv.w, bv.w);

    // Streaming store: output (512 MiB) has zero reuse; bypass cache alloc.
    __builtin_nontemporal_store(o, reinterpret_cast<vf4*>(out) + g);
}

extern "C" void kernel_launch(void* const* d_in, const int* in_sizes, int n_in,
                              void* d_out, int out_size, void* d_ws, size_t ws_size,
                              hipStream_t stream) {
    const float* x = (const float*)d_in[0];
    const float* W = (const float*)d_in[1];
    const float* B = (const float*)d_in[2];
    float* out = (float*)d_out;

    // total vf4s = BS*DEMO_DIM*FEAT_DIM / 4 = 33,554,432
    const size_t total_f4 = (size_t)BS_N * DEMO_DIM * FEAT_DIM / 4;
    const int block = 256;
    const int grid = (int)(total_f4 / block);   // 131072, exact

    demoproj_kernel<<<grid, block, 0, stream>>>(x, W, B, out);
}